// Round 13
// baseline (52.217 us; speedup 1.0000x reference)
//
#include <hip/hip_runtime.h>

// Steered 3x3 conv as per-pixel GEMM (K=256 = 64ch x 4 feats) via bf16 MFMA.
// v13: OCCUPANCY attack. r6/r8/r12 all converge at ~42us with every schedule
// variant and occupancy stuck at 21-31% -- the 64-AGPR accumulator (2 pixel
// rows/wave) caps residency at ~3 waves/SIMD and makes 18us blocks that pack
// raggedly over a 4-blocks/CU-total grid. Fix:
//  - 512-thr block, 8 waves, ONE pixel row per wave -> acc = 32 AGPR,
//    ~80 arch VGPR -> 2 blocks/CU = 32 waves/CU, half-length blocks.
//  - weights staged ONCE into LDS by DMA at prologue (r11 idea, no spill now):
//    K-loop VMEM = x-staging only -> clean counted vmcnt(2)/phase.
//  - staging: wave W stages channel W of each chunk (2 DMA/wave/phase).
//  - LDS = 32KB weights + 3x12.8KB x-buffers = 69.5KB -> 2 blocks/CU.
// B-frag: lane l -> col = l&31 (pixel), k = 16*kcg + 8*(l>>5) + r (verified r2)
// C/D:    col = lane&31, row(o) = (r&3) + 8*(r>>2) + 4*(lane>>5)  (verified r2)

typedef __bf16 bf16x8 __attribute__((ext_vector_type(8)));
typedef float  f32x16 __attribute__((ext_vector_type(16)));
typedef float  f32x4  __attribute__((ext_vector_type(4)));
typedef unsigned int u32;
typedef const __attribute__((address_space(1))) u32* gp_t;
typedef __attribute__((address_space(3))) u32* lp_t;

#define HH 128
#define WW 128
#define HW 16384
#define NCHUNK 8
#define NBUF 3
#define CHIMG 65536          // bytes per (n,ch) plane

// Weights f32[o][k] -> bf16 grouped per MFMA A-fragment:
// wb[((kcg*2+hx)*64 + o)*8 + r] = bf16(wt[o][kcg*16 + hx*8 + r])
__global__ void wt_repack(const float* __restrict__ wt,
                          unsigned short* __restrict__ wb) {
    int i = blockIdx.x * 256 + threadIdx.x;   // i = o*256 + k
    int o = i >> 8, k = i & 255;
    union { float f; u32 u; } v; v.f = wt[i];
    unsigned short b = (unsigned short)((v.u + 0x7FFF + ((v.u >> 16) & 1)) >> 16);
    int kcg = k >> 4, hxx = (k >> 3) & 1, r = k & 7;
    wb[((kcg * 2 + hxx) * 64 + o) * 8 + r] = b;
}

__global__ __launch_bounds__(512, 4) void steered_conv_mfma(
    const float* __restrict__ x, const float* __restrict__ theta,
    const unsigned short* __restrict__ wb, const float* __restrict__ bias,
    float* __restrict__ out)
{
    __shared__ unsigned short wlds[16384];                     // 32 KB weights
    __shared__ __attribute__((aligned(16))) float xs[NBUF][8][400]; // 38.4 KB

    const int tid = threadIdx.x;
    const int W = tid >> 6, lane = tid & 63;
    const int pc = lane & 31, hx = lane >> 5;

    // bijective XCD swizzle: 1024 blocks, 128/XCD = 2 whole images
    const int bb = blockIdx.x;
    const int swz = (bb & 7) * 128 + (bb >> 3);
    const int n = swz >> 6;
    const int ty = (swz >> 2) & 15, tx = swz & 3;
    const int h0 = ty * 8, w0 = tx * 32;
    const int hr = h0 + W;              // this wave's pixel row
    const int w  = w0 + pc;             // this lane's pixel column

    // ---- theta + harmonics (retire before the pipeline starts) ----
    float s1, c1;
    __sincosf(6.2831853071795864769f * theta[(n * HH + hr) * WW + w], &s1, &c1);
    const float c2 = 2.f * c1 * c1 - 1.f, s2 = 2.f * s1 * c1;

    // ---- per-lane DMA constants (channel slot = 10 rows x 40 f32 = 1600B):
    //      instr A = bytes [0,1024), instr B = [1024,1600) on lanes 0..35 ----
    const int oA = lane * 16;
    const int rA = oA / 160;
    const int cA = oA - rA * 160;
    int ghA = h0 - 1 + rA; ghA = ghA < 0 ? 0 : (ghA > 127 ? 127 : ghA);
    int srcA = ghA * 512 + w0 * 4 - 16 + cA;
    srcA = srcA < 0 ? 0 : srcA;
    const bool skA = (w0 == 0 && cA < 16) || (w0 == 96 && cA >= 144)
                   || (h0 == 0 && rA == 0);

    const int oB = 1024 + lane * 16;
    const int rB = oB / 160;
    const int cB = oB - rB * 160;
    int ghB = h0 - 1 + rB; ghB = ghB < 0 ? 0 : (ghB > 127 ? 127 : ghB);
    int srcB = ghB * 512 + w0 * 4 - 16 + cB;
    srcB = srcB < 0 ? 0 : (srcB > CHIMG - 16 ? CHIMG - 16 : srcB);
    const bool skB = (lane >= 36) || (w0 == 0 && cB < 16) || (w0 == 96 && cB >= 144)
                   || (h0 == 120 && rB == 9);

    const char* xn = (const char*)x + (size_t)n * 64 * CHIMG;

    // ---- pre-zero staging LDS for boundary tiles (skipped DMA slots = 0) ----
    if ((h0 == 0) | (h0 == 120) | (w0 == 0) | (w0 == 96)) {
        f32x4* z = (f32x4*)&xs[0][0][0];
        for (int i = tid; i < NBUF * 8 * 100; i += 512)
            z[i] = f32x4{0.f, 0.f, 0.f, 0.f};
    }
    __syncthreads();   // zeros visible before any DMA can land

    // ---- weights -> LDS (4 DMA/thread-slice; queue head) ----
    {
        const char* s = (const char*)wb + W * 1024 + lane * 16;
        char* d = (char*)wlds + W * 1024;
        #pragma unroll
        for (int r = 0; r < 4; ++r)
            __builtin_amdgcn_global_load_lds((gp_t)(s + r * 8192),
                                             (lp_t)(d + r * 8192), 16, 0, 0);
    }

    auto stage = [&](int t) {   // wave W stages channel t*8+W
        const char* s = xn + (size_t)(t * 8 + W) * CHIMG;
        char* d = (char*)&xs[t % NBUF][W][0];
        if (!skA) __builtin_amdgcn_global_load_lds((gp_t)(s + srcA), (lp_t)d, 16, 0, 0);
        if (!skB) __builtin_amdgcn_global_load_lds((gp_t)(s + srcB), (lp_t)(d + 1024), 16, 0, 0);
    };
    stage(0);
    stage(1);
    // queue: [w:4, s0:2, s1:2]; phase-head vmcnt(2) retires w + s(c)

    f32x16 acc0, acc1;
    #pragma unroll
    for (int r = 0; r < 16; ++r) { acc0[r] = 0.f; acc1[r] = 0.f; }

    const float RS  = 0.35355339059327373f;   // sqrt(2)/4
    const float HMR = 0.14644660940672627f;   // 0.5 - RS
    const float fL  = (w > 0) ? 1.f : 0.f;
    const float fR  = (w < WW - 1) ? 1.f : 0.f;

    #pragma unroll
    for (int c = 0; c < NCHUNK; ++c) {
        if (c == NCHUNK - 1) asm volatile("s_waitcnt vmcnt(0)" ::: "memory");
        else                 asm volatile("s_waitcnt vmcnt(2)" ::: "memory");
        __builtin_amdgcn_sched_barrier(0);
        __builtin_amdgcn_s_barrier();
        if (c + 2 < NCHUNK) stage(c + 2);   // WAR-safe: buf freed at barrier
        __builtin_amdgcn_sched_barrier(0);

        #pragma unroll
        for (int kc = 0; kc < 2; ++kc) {
            const int kcg = c * 2 + kc;
            bf16x8 b;
            #pragma unroll
            for (int cs = 0; cs < 2; ++cs) {
                // channel within chunk = kc*4 + hx*2 + cs; tap rows W..W+2
                const float* p = &xs[c % NBUF][0][0]
                               + (kc * 4 + hx * 2 + cs) * 400 + W * 40 + pc + 4;
                float S[3], D[3], C[3];
                #pragma unroll
                for (int rr = 0; rr < 3; ++rr) {
                    const float tL = p[rr * 40 - 1];
                    const float tC = p[rr * 40];
                    const float tR = p[rr * 40 + 1];
                    const float a = fL * tL, cc = fR * tR;
                    S[rr] = a + tC + cc;
                    D[rr] = cc - a;
                    C[rr] = tC;
                }
                const float T  = S[1] - C[1];
                const float F1 = RS * (S[0] + S[2] + T);
                const float B2 = RS * (D[0] + D[2]) + 0.5f * D[1];
                const float B3 = RS * (S[2] - S[0]) + HMR * (C[2] - C[0]);
                const float B4 = 0.5f * (T - (C[0] + C[2]));
                const float B5 = 0.5f * (D[2] - D[0]);
                b[cs*4+0] = (__bf16)C[1];
                b[cs*4+1] = (__bf16)F1;
                b[cs*4+2] = (__bf16)(c1 * B2 + s1 * B3);
                b[cs*4+3] = (__bf16)(c2 * B4 + s2 * B5);
            }
            const bf16x8 A0 = *(const bf16x8*)&wlds[((kcg*2 + hx)*64 + pc) * 8];
            const bf16x8 A1 = *(const bf16x8*)&wlds[((kcg*2 + hx)*64 + 32 + pc) * 8];
            __builtin_amdgcn_s_setprio(1);
            acc0 = __builtin_amdgcn_mfma_f32_32x32x16_bf16(A0, b, acc0, 0, 0, 0);
            acc1 = __builtin_amdgcn_mfma_f32_32x32x16_bf16(A1, b, acc1, 0, 0, 0);
            __builtin_amdgcn_s_setprio(0);
        }
    }

    const size_t hw = (size_t)HW;
    float* op = out + (size_t)n * 64 * hw + (size_t)hr * WW + w;
    #pragma unroll
    for (int r = 0; r < 16; ++r) {
        const int o = (r & 3) + 8 * (r >> 2) + 4 * hx;
        op[(size_t)o * hw]        = acc0[r] + bias[o];
        op[(size_t)(o + 32) * hw] = acc1[r] + bias[o + 32];
    }
}

extern "C" void kernel_launch(void* const* d_in, const int* in_sizes, int n_in,
                              void* d_out, int out_size, void* d_ws, size_t ws_size,
                              hipStream_t stream) {
    const float* x     = (const float*)d_in[0];
    const float* theta = (const float*)d_in[1];
    const float* wt    = (const float*)d_in[2];
    const float* bias  = (const float*)d_in[3];
    float* out = (float*)d_out;
    unsigned short* wb = (unsigned short*)d_ws;   // 32 KB bf16 weights (repacked)

    wt_repack<<<64, 256, 0, stream>>>(wt, wb);

    steered_conv_mfma<<<1024, 512, 0, stream>>>(x, theta, wb, bias, out);
}

// Round 14
// 41.029 us; speedup vs baseline: 1.2727x; 1.2727x over previous
//
#include <hip/hip_runtime.h>

// Steered 3x3 conv as per-pixel GEMM (K=256 = 64ch x 4 feats) via bf16 MFMA.
// v14: ZERO-BARRIER wave-autonomous pipeline. r6/r8/r12 all converge at 42us
// with 2 barrier+waitcnt convergence points per phase (16/kernel) at ~2.5
// waves/SIMD; pipe math (VALU ~7us, LDS ~6us, MFMA ~3.4us, HBM ~16us) says
// the wall is convergence/latency, not work. Fix: 1 wave per block (64 thr,
// grid 4096); each wave owns 2 pixel rows + PRIVATE double-buffered LDS
// (2 x [8ch][4rows][40 f32] = 10KB) -> no shared LDS -> no s_barrier at all.
// Per-wave counted VMEM queue: [s(c):5, w(c):4, s(c+1):5] -> vmcnt(5)/phase;
// weights reg-prefetched (r12 pattern); stage(c+2) after lgkmcnt(0) (WAR-safe
// by wave-local ordering). Waves self-pace; slow DMA delays only its wave.
// Cost: halo rows re-staged per wave (x-read x1.6 = +3us HBM) -- cheap vs
// removing 16 convergence points.
// B-frag: lane l -> col = l&31 (pixel), k = 16*kcg + 8*(l>>5) + r (verified r2)
// C/D:    col = lane&31, row(o) = (r&3) + 8*(r>>2) + 4*(lane>>5)  (verified r2)

typedef __bf16 bf16x8 __attribute__((ext_vector_type(8)));
typedef float  f32x16 __attribute__((ext_vector_type(16)));
typedef float  f32x4  __attribute__((ext_vector_type(4)));
typedef unsigned int u32;
typedef const __attribute__((address_space(1))) u32* gp_t;
typedef __attribute__((address_space(3))) u32* lp_t;

#define HH 128
#define WW 128
#define HW 16384
#define CHIMG 65536          // bytes per (n,ch) plane

// Weights f32[o][k] -> bf16 grouped per MFMA A-fragment:
// wb[((kcg*2+hx)*64 + o)*8 + r] = bf16(wt[o][kcg*16 + hx*8 + r])
__global__ void wt_repack(const float* __restrict__ wt,
                          unsigned short* __restrict__ wb) {
    int i = blockIdx.x * 256 + threadIdx.x;   // i = o*256 + k
    int o = i >> 8, k = i & 255;
    union { float f; u32 u; } v; v.f = wt[i];
    unsigned short b = (unsigned short)((v.u + 0x7FFF + ((v.u >> 16) & 1)) >> 16);
    int kcg = k >> 4, hxx = (k >> 3) & 1, r = k & 7;
    wb[((kcg * 2 + hxx) * 64 + o) * 8 + r] = b;
}

__global__ __launch_bounds__(64, 3) void steered_conv_mfma(
    const float* __restrict__ x, const float* __restrict__ theta,
    const unsigned short* __restrict__ wb, const float* __restrict__ bias,
    float* __restrict__ out)
{
    // wave-private staging: 2 bufs x [8 ch][4 rows][40 f32] = 10240 B
    __shared__ __attribute__((aligned(16))) float xs[2][8][4][40];

    const int lane = threadIdx.x & 63;
    const int pc = lane & 31, hx = lane >> 5;

    // bijective XCD swizzle: 4096 blocks, 512/XCD = 2 whole images
    const int bb  = blockIdx.x;
    const int swz = (bb & 7) * 512 + (bb >> 3);
    const int n   = swz >> 8;
    const int rem = swz & 255;
    const int hA  = (rem >> 2) * 2;     // wave's first pixel row (0..126)
    const int w0  = (rem & 3) * 32;
    const int w   = w0 + pc;

    // ---- per-lane DMA constants: 5 x 1024B chunks cover [8ch][4rows][160B] ----
    int soff[5];
    int skip[5];
    #pragma unroll
    for (int d = 0; d < 5; ++d) {
        const int i   = d * 1024 + lane * 16;
        const int ch  = i / 640;
        const int rm  = i - ch * 640;
        const int row = rm / 160;
        const int c16 = rm - row * 160;
        const int gh  = hA - 1 + row;
        const int ghc = gh < 0 ? 0 : (gh > 127 ? 127 : gh);
        int so = ch * CHIMG + ghc * 512 + w0 * 4 - 16 + c16;
        soff[d] = so < 0 ? 0 : so;
        skip[d] = (gh < 0) | (gh > 127) |
                  ((w0 == 0) & (c16 < 16)) | ((w0 == 96) & (c16 >= 144));
    }

    const char* xn = (const char*)x + (size_t)n * 64 * CHIMG;

    // ---- theta + harmonics (VMEM retires before the pipeline) ----
    float s1a, c1a, s1b, c1b;
    __sincosf(6.2831853071795864769f * theta[(n*HH + hA)*WW + w], &s1a, &c1a);
    __sincosf(6.2831853071795864769f * theta[(n*HH + hA+1)*WW + w], &s1b, &c1b);
    const float c2a = 2.f*c1a*c1a - 1.f, s2a = 2.f*s1a*c1a;
    const float c2b = 2.f*c1b*c1b - 1.f, s2b = 2.f*s1b*c1b;

    // ---- pre-zero own bufs when any slot will be skipped (wave-local) ----
    if (hA == 0 || hA == 126 || w0 == 0 || w0 == 96) {
        f32x4* z = (f32x4*)&xs[0][0][0][0];
        #pragma unroll
        for (int i = 0; i < 10; ++i)          // 2560 f32 = 640 f32x4 / 64 lanes
            z[lane + i * 64] = f32x4{0.f, 0.f, 0.f, 0.f};
        asm volatile("s_waitcnt lgkmcnt(0)" ::: "memory");
    }

    auto stage = [&](int t) {                  // stages channels t*8..t*8+7
        const char* sb = xn + (size_t)(t * 8) * CHIMG;
        char* db = (char*)&xs[t & 1][0][0][0];
        #pragma unroll
        for (int d = 0; d < 5; ++d)
            if (!skip[d])
                __builtin_amdgcn_global_load_lds((gp_t)(sb + soff[d]),
                                                 (lp_t)(db + d * 1024), 16, 0, 0);
    };

    const unsigned short* wbl = wb + (hx * 64 + pc) * 8;
    bf16x8 wE0, wE1, wE2, wE3, wO0, wO1, wO2, wO3;

    // prologue queue: [s(0):5, w(0):4, s(1):5]
    stage(0);
    __builtin_amdgcn_sched_barrier(0);
    {
        const unsigned short* wr = wbl;
        wE0 = *(const bf16x8*)(wr);
        wE1 = *(const bf16x8*)(wr + 256);
        wE2 = *(const bf16x8*)(wr + 1024);
        wE3 = *(const bf16x8*)(wr + 1280);
    }
    __builtin_amdgcn_sched_barrier(0);
    stage(1);
    __builtin_amdgcn_sched_barrier(0);

    f32x16 acc00, acc01, acc10, acc11;
    #pragma unroll
    for (int r = 0; r < 16; ++r) { acc00[r]=0.f; acc01[r]=0.f; acc10[r]=0.f; acc11[r]=0.f; }

    const float RS  = 0.35355339059327373f;   // sqrt(2)/4
    const float HMR = 0.14644660940672627f;   // 0.5 - RS

    #pragma unroll
    for (int c = 0; c < 8; ++c) {
        // retire s(c)+w(c); leave s(c+1) in flight (wave-private wait)
        if (c == 7) asm volatile("s_waitcnt vmcnt(0)" ::: "memory");
        else        asm volatile("s_waitcnt vmcnt(5)" ::: "memory");
        __builtin_amdgcn_sched_barrier(0);
        if (c < 7) {   // weight prefetch for phase c+1 (queue pos before s(c+2))
            const unsigned short* wr = wbl + (c + 1) * 2048;
            if ((c + 1) & 1) {
                wO0 = *(const bf16x8*)(wr);
                wO1 = *(const bf16x8*)(wr + 256);
                wO2 = *(const bf16x8*)(wr + 1024);
                wO3 = *(const bf16x8*)(wr + 1280);
            } else {
                wE0 = *(const bf16x8*)(wr);
                wE1 = *(const bf16x8*)(wr + 256);
                wE2 = *(const bf16x8*)(wr + 1024);
                wE3 = *(const bf16x8*)(wr + 1280);
            }
            __builtin_amdgcn_sched_barrier(0);
        }

        const bf16x8 A00 = (c & 1) ? wO0 : wE0;
        const bf16x8 A01 = (c & 1) ? wO1 : wE1;
        const bf16x8 A10 = (c & 1) ? wO2 : wE2;
        const bf16x8 A11 = (c & 1) ? wO3 : wE3;

        const float* tb = &xs[c & 1][0][0][0];
        #pragma unroll
        for (int kc = 0; kc < 2; ++kc) {
            bf16x8 b0, b1;
            #pragma unroll
            for (int cs = 0; cs < 2; ++cs) {
                const float* t = tb + (kc * 4 + hx * 2 + cs) * 160 + pc + 3;
                const float t00=t[0],   t01=t[1],   t02=t[2];
                const float t10=t[40],  t11=t[41],  t12=t[42];
                const float t20=t[80],  t21=t[81],  t22=t[82];
                const float t30=t[120], t31=t[121], t32=t[122];
                const float S0=t00+t01+t02, S1=t10+t11+t12;
                const float S2=t20+t21+t22, S3=t30+t31+t32;
                const float D0=t02-t00, D1=t12-t10, D2=t22-t20, D3=t32-t30;
                {   // pixel row hA (tap rows 0,1,2)
                    const float F1 = RS * (S0 + S2 + S1 - t11);
                    const float B2 = RS * (D0 + D2) + 0.5f * D1;
                    const float B3 = RS * (S2 - S0) + HMR * (t21 - t01);
                    const float B4 = 0.5f * (S1 - t11 - t01 - t21);
                    const float B5 = 0.5f * (D2 - D0);
                    b0[cs*4+0] = (__bf16)t11;
                    b0[cs*4+1] = (__bf16)F1;
                    b0[cs*4+2] = (__bf16)(c1a * B2 + s1a * B3);
                    b0[cs*4+3] = (__bf16)(c2a * B4 + s2a * B5);
                }
                {   // pixel row hA+1 (tap rows 1,2,3)
                    const float F1 = RS * (S1 + S3 + S2 - t21);
                    const float B2 = RS * (D1 + D3) + 0.5f * D2;
                    const float B3 = RS * (S3 - S1) + HMR * (t31 - t11);
                    const float B4 = 0.5f * (S2 - t21 - t11 - t31);
                    const float B5 = 0.5f * (D3 - D1);
                    b1[cs*4+0] = (__bf16)t21;
                    b1[cs*4+1] = (__bf16)F1;
                    b1[cs*4+2] = (__bf16)(c1b * B2 + s1b * B3);
                    b1[cs*4+3] = (__bf16)(c2b * B4 + s2b * B5);
                }
            }
            const bf16x8 A0 = kc ? A10 : A00;
            const bf16x8 A1 = kc ? A11 : A01;
            __builtin_amdgcn_s_setprio(1);
            acc00 = __builtin_amdgcn_mfma_f32_32x32x16_bf16(A0, b0, acc00, 0, 0, 0);
            acc01 = __builtin_amdgcn_mfma_f32_32x32x16_bf16(A1, b0, acc01, 0, 0, 0);
            acc10 = __builtin_amdgcn_mfma_f32_32x32x16_bf16(A0, b1, acc10, 0, 0, 0);
            acc11 = __builtin_amdgcn_mfma_f32_32x32x16_bf16(A1, b1, acc11, 0, 0, 0);
            __builtin_amdgcn_s_setprio(0);
        }
        // all ds_reads of buf[c&1] complete -> safe to overwrite (wave-local)
        asm volatile("s_waitcnt lgkmcnt(0)" ::: "memory");
        __builtin_amdgcn_sched_barrier(0);
        if (c < 6) stage(c + 2);
        __builtin_amdgcn_sched_barrier(0);
    }

    const size_t hw = (size_t)HW;
    float* op = out + (size_t)n * 64 * hw + (size_t)hA * WW + w;
    #pragma unroll
    for (int r = 0; r < 16; ++r) {
        const int o = (r & 3) + 8 * (r >> 2) + 4 * hx;
        const float bo = bias[o], bo2 = bias[o + 32];
        op[(size_t)o * hw]             = acc00[r] + bo;
        op[(size_t)(o + 32) * hw]      = acc01[r] + bo2;
        op[(size_t)o * hw + WW]        = acc10[r] + bo;
        op[(size_t)(o + 32) * hw + WW] = acc11[r] + bo2;
    }
}

extern "C" void kernel_launch(void* const* d_in, const int* in_sizes, int n_in,
                              void* d_out, int out_size, void* d_ws, size_t ws_size,
                              hipStream_t stream) {
    const float* x     = (const float*)d_in[0];
    const float* theta = (const float*)d_in[1];
    const float* wt    = (const float*)d_in[2];
    const float* bias  = (const float*)d_in[3];
    float* out = (float*)d_out;
    unsigned short* wb = (unsigned short*)d_ws;   // 32 KB bf16 weights (repacked)

    wt_repack<<<64, 256, 0, stream>>>(wt, wb);

    steered_conv_mfma<<<4096, 64, 0, stream>>>(x, theta, wb, bias, out);
}

// Round 15
// 37.342 us; speedup vs baseline: 1.3984x; 1.0987x over previous
//
#include <hip/hip_runtime.h>

// Steered 3x3 conv as per-pixel GEMM (K=256 = 64ch x 4 feats) via bf16 MFMA.
// v15 = r14's zero-barrier wave-autonomous skeleton + HALVED compute stream.
// Cross-round invariant (r6..r14): VALUBusy pins ~40%, dur tracks per-wave
// issue work (r13: 1.5x work -> 1.25x dur; occupancy moves nothing). So cut
// the work:
//  - channel-pair (cs=0,1) computed lock-step as f32x2 -> v_pk_fma_f32 etc.
//    (2x f32 VALU throughput); pair taps loaded as {t[X], t[X+160]} -> the
//    compiler merges to ds_read2_b32 (1 LDS instr / 2 taps).
//  - constants folded into repacked weights: W1'=RS*W1, W2'=RS*W2, W3'=.5*W3
//    with B2'=D0+D2+sqrt2*D1, B3'=(S2-S0)+(sqrt2-1)*(C2-C0), B4'=T-(C0+C2),
//    B5'=D2-D0  (exact algebra, same rounding points -> same absmax).
// B-frag: lane l -> col = l&31 (pixel), k = 16*kcg + 8*(l>>5) + r (verified r2)
// C/D:    col = lane&31, row(o) = (r&3) + 8*(r>>2) + 4*(lane>>5)  (verified r2)

typedef __bf16 bf16x8 __attribute__((ext_vector_type(8)));
typedef float  f32x16 __attribute__((ext_vector_type(16)));
typedef float  f32x4  __attribute__((ext_vector_type(4)));
typedef float  f32x2  __attribute__((ext_vector_type(2)));
typedef unsigned int u32;
typedef const __attribute__((address_space(1))) u32* gp_t;
typedef __attribute__((address_space(3))) u32* lp_t;

#define HH 128
#define WW 128
#define HW 16384
#define CHIMG 65536          // bytes per (n,ch) plane

// Weights f32[o][k] -> bf16, pre-scaled per feature and grouped per MFMA
// A-fragment: wb[((kcg*2+hx)*64 + o)*8 + r] = bf16(sc[k&3] * wt[o][k])
__global__ void wt_repack(const float* __restrict__ wt,
                          unsigned short* __restrict__ wb) {
    int i = blockIdx.x * 256 + threadIdx.x;   // i = o*256 + k
    int o = i >> 8, k = i & 255;
    const float sc[4] = {1.f, 0.35355339059327373f, 0.35355339059327373f, 0.5f};
    union { float f; u32 u; } v; v.f = wt[i] * sc[k & 3];
    unsigned short b = (unsigned short)((v.u + 0x7FFF + ((v.u >> 16) & 1)) >> 16);
    int kcg = k >> 4, hxx = (k >> 3) & 1, r = k & 7;
    wb[((kcg * 2 + hxx) * 64 + o) * 8 + r] = b;
}

__global__ __launch_bounds__(64, 3) void steered_conv_mfma(
    const float* __restrict__ x, const float* __restrict__ theta,
    const unsigned short* __restrict__ wb, const float* __restrict__ bias,
    float* __restrict__ out)
{
    // wave-private staging: 2 bufs x [8 ch][4 rows][40 f32] = 10240 B
    __shared__ __attribute__((aligned(16))) float xs[2][8][4][40];

    const int lane = threadIdx.x & 63;
    const int pc = lane & 31, hx = lane >> 5;

    // bijective XCD swizzle: 4096 blocks, 512/XCD = 2 whole images
    const int bb  = blockIdx.x;
    const int swz = (bb & 7) * 512 + (bb >> 3);
    const int n   = swz >> 8;
    const int rem = swz & 255;
    const int hA  = (rem >> 2) * 2;     // wave's first pixel row (0..126)
    const int w0  = (rem & 3) * 32;
    const int w   = w0 + pc;

    // ---- per-lane DMA constants: 5 x 1024B chunks cover [8ch][4rows][160B] ----
    int soff[5];
    int skip[5];
    #pragma unroll
    for (int d = 0; d < 5; ++d) {
        const int i   = d * 1024 + lane * 16;
        const int ch  = i / 640;
        const int rm  = i - ch * 640;
        const int row = rm / 160;
        const int c16 = rm - row * 160;
        const int gh  = hA - 1 + row;
        const int ghc = gh < 0 ? 0 : (gh > 127 ? 127 : gh);
        int so = ch * CHIMG + ghc * 512 + w0 * 4 - 16 + c16;
        soff[d] = so < 0 ? 0 : so;
        skip[d] = (gh < 0) | (gh > 127) |
                  ((w0 == 0) & (c16 < 16)) | ((w0 == 96) & (c16 >= 144));
    }

    const char* xn = (const char*)x + (size_t)n * 64 * CHIMG;

    // ---- theta + harmonics (VMEM retires before the pipeline) ----
    float s1a, c1a, s1b, c1b;
    __sincosf(6.2831853071795864769f * theta[(n*HH + hA)*WW + w], &s1a, &c1a);
    __sincosf(6.2831853071795864769f * theta[(n*HH + hA+1)*WW + w], &s1b, &c1b);
    const f32x2 C1A = {c1a, c1a}, S1A = {s1a, s1a};
    const f32x2 C2A = {2.f*c1a*c1a - 1.f, 2.f*c1a*c1a - 1.f};
    const f32x2 S2A = {2.f*s1a*c1a, 2.f*s1a*c1a};
    const f32x2 C1B = {c1b, c1b}, S1B = {s1b, s1b};
    const f32x2 C2B = {2.f*c1b*c1b - 1.f, 2.f*c1b*c1b - 1.f};
    const f32x2 S2B = {2.f*s1b*c1b, 2.f*s1b*c1b};

    // ---- pre-zero own bufs when any slot will be skipped (wave-local) ----
    if (hA == 0 || hA == 126 || w0 == 0 || w0 == 96) {
        f32x4* z = (f32x4*)&xs[0][0][0][0];
        #pragma unroll
        for (int i = 0; i < 10; ++i)
            z[lane + i * 64] = f32x4{0.f, 0.f, 0.f, 0.f};
        asm volatile("s_waitcnt lgkmcnt(0)" ::: "memory");
    }

    auto stage = [&](int t) {                  // stages channels t*8..t*8+7
        const char* sb = xn + (size_t)(t * 8) * CHIMG;
        char* db = (char*)&xs[t & 1][0][0][0];
        #pragma unroll
        for (int d = 0; d < 5; ++d)
            if (!skip[d])
                __builtin_amdgcn_global_load_lds((gp_t)(sb + soff[d]),
                                                 (lp_t)(db + d * 1024), 16, 0, 0);
    };

    const unsigned short* wbl = wb + (hx * 64 + pc) * 8;
    bf16x8 wE0, wE1, wE2, wE3, wO0, wO1, wO2, wO3;

    // prologue queue: [s(0):5, w(0):4, s(1):5]
    stage(0);
    __builtin_amdgcn_sched_barrier(0);
    {
        const unsigned short* wr = wbl;
        wE0 = *(const bf16x8*)(wr);
        wE1 = *(const bf16x8*)(wr + 256);
        wE2 = *(const bf16x8*)(wr + 1024);
        wE3 = *(const bf16x8*)(wr + 1280);
    }
    __builtin_amdgcn_sched_barrier(0);
    stage(1);
    __builtin_amdgcn_sched_barrier(0);

    f32x16 acc00, acc01, acc10, acc11;
    #pragma unroll
    for (int r = 0; r < 16; ++r) { acc00[r]=0.f; acc01[r]=0.f; acc10[r]=0.f; acc11[r]=0.f; }

    const f32x2 SQ2 = {1.4142135623730951f, 1.4142135623730951f};
    const f32x2 R41 = {0.4142135623730951f, 0.4142135623730951f};

    #pragma unroll
    for (int c = 0; c < 8; ++c) {
        if (c == 7) asm volatile("s_waitcnt vmcnt(0)" ::: "memory");
        else        asm volatile("s_waitcnt vmcnt(5)" ::: "memory");
        __builtin_amdgcn_sched_barrier(0);
        if (c < 7) {
            const unsigned short* wr = wbl + (c + 1) * 2048;
            if ((c + 1) & 1) {
                wO0 = *(const bf16x8*)(wr);
                wO1 = *(const bf16x8*)(wr + 256);
                wO2 = *(const bf16x8*)(wr + 1024);
                wO3 = *(const bf16x8*)(wr + 1280);
            } else {
                wE0 = *(const bf16x8*)(wr);
                wE1 = *(const bf16x8*)(wr + 256);
                wE2 = *(const bf16x8*)(wr + 1024);
                wE3 = *(const bf16x8*)(wr + 1280);
            }
            __builtin_amdgcn_sched_barrier(0);
        }

        const bf16x8 A00 = (c & 1) ? wO0 : wE0;
        const bf16x8 A01 = (c & 1) ? wO1 : wE1;
        const bf16x8 A10 = (c & 1) ? wO2 : wE2;
        const bf16x8 A11 = (c & 1) ? wO3 : wE3;

        const float* tb = &xs[c & 1][0][0][0];
        #pragma unroll
        for (int kc = 0; kc < 2; ++kc) {
            // channel pair (cs=0 at t[.], cs=1 at t[.+160]) computed packed
            const float* t = tb + (kc * 4 + hx * 2) * 160 + pc + 3;
            #define PAIR(off) (f32x2){t[off], t[(off) + 160]}
            const f32x2 L0 = PAIR(0),   Cc0 = PAIR(1),   R0 = PAIR(2);
            const f32x2 L1 = PAIR(40),  Cc1 = PAIR(41),  R1 = PAIR(42);
            const f32x2 L2 = PAIR(80),  Cc2 = PAIR(81),  R2 = PAIR(82);
            const f32x2 L3 = PAIR(120), Cc3 = PAIR(121), R3 = PAIR(122);
            #undef PAIR
            const f32x2 S0 = L0 + Cc0 + R0, S1 = L1 + Cc1 + R1;
            const f32x2 S2 = L2 + Cc2 + R2, S3 = L3 + Cc3 + R3;
            const f32x2 D0 = R0 - L0, D1 = R1 - L1;
            const f32x2 D2 = R2 - L2, D3 = R3 - L3;

            bf16x8 b0, b1;
            {   // pixel row hA (tap rows 0,1,2)
                const f32x2 T  = S1 - Cc1;
                const f32x2 F1 = S0 + S2 + T;
                const f32x2 B2 = (D0 + D2) + SQ2 * D1;
                const f32x2 B3 = (S2 - S0) + R41 * (Cc2 - Cc0);
                const f32x2 B4 = T - (Cc0 + Cc2);
                const f32x2 B5 = D2 - D0;
                const f32x2 F2 = C1A * B2 + S1A * B3;
                const f32x2 F3 = C2A * B4 + S2A * B5;
                b0[0]=(__bf16)Cc1.x; b0[1]=(__bf16)F1.x; b0[2]=(__bf16)F2.x; b0[3]=(__bf16)F3.x;
                b0[4]=(__bf16)Cc1.y; b0[5]=(__bf16)F1.y; b0[6]=(__bf16)F2.y; b0[7]=(__bf16)F3.y;
            }
            {   // pixel row hA+1 (tap rows 1,2,3)
                const f32x2 T  = S2 - Cc2;
                const f32x2 F1 = S1 + S3 + T;
                const f32x2 B2 = (D1 + D3) + SQ2 * D2;
                const f32x2 B3 = (S3 - S1) + R41 * (Cc3 - Cc1);
                const f32x2 B4 = T - (Cc1 + Cc3);
                const f32x2 B5 = D3 - D1;
                const f32x2 F2 = C1B * B2 + S1B * B3;
                const f32x2 F3 = C2B * B4 + S2B * B5;
                b1[0]=(__bf16)Cc2.x; b1[1]=(__bf16)F1.x; b1[2]=(__bf16)F2.x; b1[3]=(__bf16)F3.x;
                b1[4]=(__bf16)Cc2.y; b1[5]=(__bf16)F1.y; b1[6]=(__bf16)F2.y; b1[7]=(__bf16)F3.y;
            }
            const bf16x8 A0 = kc ? A10 : A00;
            const bf16x8 A1 = kc ? A11 : A01;
            __builtin_amdgcn_s_setprio(1);
            acc00 = __builtin_amdgcn_mfma_f32_32x32x16_bf16(A0, b0, acc00, 0, 0, 0);
            acc01 = __builtin_amdgcn_mfma_f32_32x32x16_bf16(A1, b0, acc01, 0, 0, 0);
            acc10 = __builtin_amdgcn_mfma_f32_32x32x16_bf16(A0, b1, acc10, 0, 0, 0);
            acc11 = __builtin_amdgcn_mfma_f32_32x32x16_bf16(A1, b1, acc11, 0, 0, 0);
            __builtin_amdgcn_s_setprio(0);
        }
        asm volatile("s_waitcnt lgkmcnt(0)" ::: "memory");
        __builtin_amdgcn_sched_barrier(0);
        if (c < 6) stage(c + 2);
        __builtin_amdgcn_sched_barrier(0);
    }

    const size_t hw = (size_t)HW;
    float* op = out + (size_t)n * 64 * hw + (size_t)hA * WW + w;
    #pragma unroll
    for (int r = 0; r < 16; ++r) {
        const int o = (r & 3) + 8 * (r >> 2) + 4 * hx;
        const float bo = bias[o], bo2 = bias[o + 32];
        op[(size_t)o * hw]             = acc00[r] + bo;
        op[(size_t)(o + 32) * hw]      = acc01[r] + bo2;
        op[(size_t)o * hw + WW]        = acc10[r] + bo;
        op[(size_t)(o + 32) * hw + WW] = acc11[r] + bo2;
    }
}

extern "C" void kernel_launch(void* const* d_in, const int* in_sizes, int n_in,
                              void* d_out, int out_size, void* d_ws, size_t ws_size,
                              hipStream_t stream) {
    const float* x     = (const float*)d_in[0];
    const float* theta = (const float*)d_in[1];
    const float* wt    = (const float*)d_in[2];
    const float* bias  = (const float*)d_in[3];
    float* out = (float*)d_out;
    unsigned short* wb = (unsigned short*)d_ws;   // 32 KB bf16 weights (repacked)

    wt_repack<<<64, 256, 0, stream>>>(wt, wb);

    steered_conv_mfma<<<4096, 64, 0, stream>>>(x, theta, wb, bias, out);
}

// Round 16
// 36.624 us; speedup vs baseline: 1.4258x; 1.0196x over previous
//
#include <hip/hip_runtime.h>

// Steered 3x3 conv as per-pixel GEMM (K=256 = 64ch x 4 feats) via bf16 MFMA.
// v16 = v15's wave-autonomous pipeline, but 4 wave-units per 256-thr block
// (ZERO intra-block barriers; each wave keeps a PRIVATE 10KB LDS slice).
// r15 diagnosis: VALU halved (VALUBusy 36->22%) but dur -10% only; occupancy
// 16% ~= 5 waves/CU despite a 12/CU VGPR cap -> 4096 single-wave workgroups
// are dispatch/residency-limited (G11). Fix: 1024 blocks x 4 waves = same
// wave code, 4x fewer dispatches, 3 blocks/CU x 4 waves = 12 waves/CU steady.
// Block's 4 units share the image row-band (w0 = 0/32/64/96) -> L2 locality.
// B-frag: lane l -> col = l&31 (pixel), k = 16*kcg + 8*(l>>5) + r (verified r2)
// C/D:    col = lane&31, row(o) = (r&3) + 8*(r>>2) + 4*(lane>>5)  (verified r2)

typedef __bf16 bf16x8 __attribute__((ext_vector_type(8)));
typedef float  f32x16 __attribute__((ext_vector_type(16)));
typedef float  f32x4  __attribute__((ext_vector_type(4)));
typedef float  f32x2  __attribute__((ext_vector_type(2)));
typedef unsigned int u32;
typedef const __attribute__((address_space(1))) u32* gp_t;
typedef __attribute__((address_space(3))) u32* lp_t;

#define HH 128
#define WW 128
#define HW 16384
#define CHIMG 65536          // bytes per (n,ch) plane

// Weights f32[o][k] -> bf16, pre-scaled per feature and grouped per MFMA
// A-fragment: wb[((kcg*2+hx)*64 + o)*8 + r] = bf16(sc[k&3] * wt[o][k])
__global__ void wt_repack(const float* __restrict__ wt,
                          unsigned short* __restrict__ wb) {
    int i = blockIdx.x * 256 + threadIdx.x;   // i = o*256 + k
    int o = i >> 8, k = i & 255;
    const float sc[4] = {1.f, 0.35355339059327373f, 0.35355339059327373f, 0.5f};
    union { float f; u32 u; } v; v.f = wt[i] * sc[k & 3];
    unsigned short b = (unsigned short)((v.u + 0x7FFF + ((v.u >> 16) & 1)) >> 16);
    int kcg = k >> 4, hxx = (k >> 3) & 1, r = k & 7;
    wb[((kcg * 2 + hxx) * 64 + o) * 8 + r] = b;
}

__global__ __launch_bounds__(256, 3) void steered_conv_mfma(
    const float* __restrict__ x, const float* __restrict__ theta,
    const unsigned short* __restrict__ wb, const float* __restrict__ bias,
    float* __restrict__ out)
{
    // 4 wave-private staging slices: [wave][2 bufs][8 ch][4 rows][40 f32]
    __shared__ __attribute__((aligned(16))) float xs[4][2][8][4][40]; // 40.96KB

    const int tid  = threadIdx.x;
    const int W    = tid >> 6;
    const int lane = tid & 63;
    const int pc = lane & 31, hx = lane >> 5;

    // bijective XCD swizzle over 1024 blocks; block covers 4 wave-units
    const int bb   = blockIdx.x;
    const int swz  = (bb & 7) * 128 + (bb >> 3);
    const int unit = swz * 4 + W;
    const int n    = unit >> 8;
    const int rem  = unit & 255;
    const int hA   = (rem >> 2) * 2;    // wave's first pixel row (0..126)
    const int w0   = (rem & 3) * 32;
    const int w    = w0 + pc;

    // ---- per-lane DMA constants: 5 x 1024B chunks cover [8ch][4rows][160B] ----
    int soff[5];
    int skip[5];
    #pragma unroll
    for (int d = 0; d < 5; ++d) {
        const int i   = d * 1024 + lane * 16;
        const int ch  = i / 640;
        const int rm  = i - ch * 640;
        const int row = rm / 160;
        const int c16 = rm - row * 160;
        const int gh  = hA - 1 + row;
        const int ghc = gh < 0 ? 0 : (gh > 127 ? 127 : gh);
        int so = ch * CHIMG + ghc * 512 + w0 * 4 - 16 + c16;
        soff[d] = so < 0 ? 0 : so;
        skip[d] = (gh < 0) | (gh > 127) |
                  ((w0 == 0) & (c16 < 16)) | ((w0 == 96) & (c16 >= 144));
    }

    const char* xn = (const char*)x + (size_t)n * 64 * CHIMG;

    // ---- theta + harmonics (VMEM retires before the pipeline) ----
    float s1a, c1a, s1b, c1b;
    __sincosf(6.2831853071795864769f * theta[(n*HH + hA)*WW + w], &s1a, &c1a);
    __sincosf(6.2831853071795864769f * theta[(n*HH + hA+1)*WW + w], &s1b, &c1b);
    const f32x2 C1A = {c1a, c1a}, S1A = {s1a, s1a};
    const f32x2 C2A = {2.f*c1a*c1a - 1.f, 2.f*c1a*c1a - 1.f};
    const f32x2 S2A = {2.f*s1a*c1a, 2.f*s1a*c1a};
    const f32x2 C1B = {c1b, c1b}, S1B = {s1b, s1b};
    const f32x2 C2B = {2.f*c1b*c1b - 1.f, 2.f*c1b*c1b - 1.f};
    const f32x2 S2B = {2.f*s1b*c1b, 2.f*s1b*c1b};

    // ---- pre-zero own bufs when any slot will be skipped (wave-local) ----
    if (hA == 0 || hA == 126 || w0 == 0 || w0 == 96) {
        f32x4* z = (f32x4*)&xs[W][0][0][0][0];
        #pragma unroll
        for (int i = 0; i < 10; ++i)
            z[lane + i * 64] = f32x4{0.f, 0.f, 0.f, 0.f};
        asm volatile("s_waitcnt lgkmcnt(0)" ::: "memory");
    }

    auto stage = [&](int t) {                  // stages channels t*8..t*8+7
        const char* sb = xn + (size_t)(t * 8) * CHIMG;
        char* db = (char*)&xs[W][t & 1][0][0][0];
        #pragma unroll
        for (int d = 0; d < 5; ++d)
            if (!skip[d])
                __builtin_amdgcn_global_load_lds((gp_t)(sb + soff[d]),
                                                 (lp_t)(db + d * 1024), 16, 0, 0);
    };

    const unsigned short* wbl = wb + (hx * 64 + pc) * 8;
    bf16x8 wE0, wE1, wE2, wE3, wO0, wO1, wO2, wO3;

    // prologue queue: [s(0):5, w(0):4, s(1):5]
    stage(0);
    __builtin_amdgcn_sched_barrier(0);
    {
        const unsigned short* wr = wbl;
        wE0 = *(const bf16x8*)(wr);
        wE1 = *(const bf16x8*)(wr + 256);
        wE2 = *(const bf16x8*)(wr + 1024);
        wE3 = *(const bf16x8*)(wr + 1280);
    }
    __builtin_amdgcn_sched_barrier(0);
    stage(1);
    __builtin_amdgcn_sched_barrier(0);

    f32x16 acc00, acc01, acc10, acc11;
    #pragma unroll
    for (int r = 0; r < 16; ++r) { acc00[r]=0.f; acc01[r]=0.f; acc10[r]=0.f; acc11[r]=0.f; }

    const f32x2 SQ2 = {1.4142135623730951f, 1.4142135623730951f};
    const f32x2 R41 = {0.4142135623730951f, 0.4142135623730951f};

    #pragma unroll
    for (int c = 0; c < 8; ++c) {
        if (c == 7) asm volatile("s_waitcnt vmcnt(0)" ::: "memory");
        else        asm volatile("s_waitcnt vmcnt(5)" ::: "memory");
        __builtin_amdgcn_sched_barrier(0);
        if (c < 7) {
            const unsigned short* wr = wbl + (c + 1) * 2048;
            if ((c + 1) & 1) {
                wO0 = *(const bf16x8*)(wr);
                wO1 = *(const bf16x8*)(wr + 256);
                wO2 = *(const bf16x8*)(wr + 1024);
                wO3 = *(const bf16x8*)(wr + 1280);
            } else {
                wE0 = *(const bf16x8*)(wr);
                wE1 = *(const bf16x8*)(wr + 256);
                wE2 = *(const bf16x8*)(wr + 1024);
                wE3 = *(const bf16x8*)(wr + 1280);
            }
            __builtin_amdgcn_sched_barrier(0);
        }

        const bf16x8 A00 = (c & 1) ? wO0 : wE0;
        const bf16x8 A01 = (c & 1) ? wO1 : wE1;
        const bf16x8 A10 = (c & 1) ? wO2 : wE2;
        const bf16x8 A11 = (c & 1) ? wO3 : wE3;

        const float* tb = &xs[W][c & 1][0][0][0];
        #pragma unroll
        for (int kc = 0; kc < 2; ++kc) {
            // channel pair (cs=0 at t[.], cs=1 at t[.+160]) computed packed
            const float* t = tb + (kc * 4 + hx * 2) * 160 + pc + 3;
            #define PAIR(off) (f32x2){t[off], t[(off) + 160]}
            const f32x2 L0 = PAIR(0),   Cc0 = PAIR(1),   R0 = PAIR(2);
            const f32x2 L1 = PAIR(40),  Cc1 = PAIR(41),  R1 = PAIR(42);
            const f32x2 L2 = PAIR(80),  Cc2 = PAIR(81),  R2 = PAIR(82);
            const f32x2 L3 = PAIR(120), Cc3 = PAIR(121), R3 = PAIR(122);
            #undef PAIR
            const f32x2 S0 = L0 + Cc0 + R0, S1 = L1 + Cc1 + R1;
            const f32x2 S2 = L2 + Cc2 + R2, S3 = L3 + Cc3 + R3;
            const f32x2 D0 = R0 - L0, D1 = R1 - L1;
            const f32x2 D2 = R2 - L2, D3 = R3 - L3;

            bf16x8 b0, b1;
            {   // pixel row hA (tap rows 0,1,2)
                const f32x2 T  = S1 - Cc1;
                const f32x2 F1 = S0 + S2 + T;
                const f32x2 B2 = (D0 + D2) + SQ2 * D1;
                const f32x2 B3 = (S2 - S0) + R41 * (Cc2 - Cc0);
                const f32x2 B4 = T - (Cc0 + Cc2);
                const f32x2 B5 = D2 - D0;
                const f32x2 F2 = C1A * B2 + S1A * B3;
                const f32x2 F3 = C2A * B4 + S2A * B5;
                b0[0]=(__bf16)Cc1.x; b0[1]=(__bf16)F1.x; b0[2]=(__bf16)F2.x; b0[3]=(__bf16)F3.x;
                b0[4]=(__bf16)Cc1.y; b0[5]=(__bf16)F1.y; b0[6]=(__bf16)F2.y; b0[7]=(__bf16)F3.y;
            }
            {   // pixel row hA+1 (tap rows 1,2,3)
                const f32x2 T  = S2 - Cc2;
                const f32x2 F1 = S1 + S3 + T;
                const f32x2 B2 = (D1 + D3) + SQ2 * D2;
                const f32x2 B3 = (S3 - S1) + R41 * (Cc3 - Cc1);
                const f32x2 B4 = T - (Cc1 + Cc3);
                const f32x2 B5 = D3 - D1;
                const f32x2 F2 = C1B * B2 + S1B * B3;
                const f32x2 F3 = C2B * B4 + S2B * B5;
                b1[0]=(__bf16)Cc2.x; b1[1]=(__bf16)F1.x; b1[2]=(__bf16)F2.x; b1[3]=(__bf16)F3.x;
                b1[4]=(__bf16)Cc2.y; b1[5]=(__bf16)F1.y; b1[6]=(__bf16)F2.y; b1[7]=(__bf16)F3.y;
            }
            const bf16x8 A0 = kc ? A10 : A00;
            const bf16x8 A1 = kc ? A11 : A01;
            __builtin_amdgcn_s_setprio(1);
            acc00 = __builtin_amdgcn_mfma_f32_32x32x16_bf16(A0, b0, acc00, 0, 0, 0);
            acc01 = __builtin_amdgcn_mfma_f32_32x32x16_bf16(A1, b0, acc01, 0, 0, 0);
            acc10 = __builtin_amdgcn_mfma_f32_32x32x16_bf16(A0, b1, acc10, 0, 0, 0);
            acc11 = __builtin_amdgcn_mfma_f32_32x32x16_bf16(A1, b1, acc11, 0, 0, 0);
            __builtin_amdgcn_s_setprio(0);
        }
        asm volatile("s_waitcnt lgkmcnt(0)" ::: "memory");
        __builtin_amdgcn_sched_barrier(0);
        if (c < 6) stage(c + 2);
        __builtin_amdgcn_sched_barrier(0);
    }

    const size_t hw = (size_t)HW;
    float* op = out + (size_t)n * 64 * hw + (size_t)hA * WW + w;
    #pragma unroll
    for (int r = 0; r < 16; ++r) {
        const int o = (r & 3) + 8 * (r >> 2) + 4 * hx;
        const float bo = bias[o], bo2 = bias[o + 32];
        op[(size_t)o * hw]             = acc00[r] + bo;
        op[(size_t)(o + 32) * hw]      = acc01[r] + bo2;
        op[(size_t)o * hw + WW]        = acc10[r] + bo;
        op[(size_t)(o + 32) * hw + WW] = acc11[r] + bo2;
    }
}

extern "C" void kernel_launch(void* const* d_in, const int* in_sizes, int n_in,
                              void* d_out, int out_size, void* d_ws, size_t ws_size,
                              hipStream_t stream) {
    const float* x     = (const float*)d_in[0];
    const float* theta = (const float*)d_in[1];
    const float* wt    = (const float*)d_in[2];
    const float* bias  = (const float*)d_in[3];
    float* out = (float*)d_out;
    unsigned short* wb = (unsigned short*)d_ws;   // 32 KB bf16 weights (repacked)

    wt_repack<<<64, 256, 0, stream>>>(wt, wb);

    steered_conv_mfma<<<1024, 256, 0, stream>>>(x, theta, wb, bias, out);
}